// Round 3
// baseline (3437.400 us; speedup 1.0000x reference)
//
#include <hip/hip_runtime.h>
#include <hip/hip_bf16.h>

#define HH 128   // hidden
#define EDD 64   // edge_dim
#define NLAYER 3
#define LN_EPS 1e-5f

// ---------------------------------------------------------------------------
// Edge kernel: for 4 edges per wave-iteration:
//   e = edge_attr @ We + be ; msg = relu(s[src] + e) ; atomicAdd into agg[dst]
// We (64x128 f32 = 32KB) staged in LDS, reads amortized over 4 edges.
// attr rows staged in wave-private LDS (same-wave in-order DS => no barrier).
// ---------------------------------------------------------------------------
__global__ __launch_bounds__(256) void gine_edge(
    const float* __restrict__ s,
    const int* __restrict__ src,
    const int* __restrict__ dst,
    const float* __restrict__ ea,
    const float* __restrict__ We,   // [EDD][HH] slice for this layer
    const float* __restrict__ be,   // [HH]
    float* __restrict__ agg,
    int E)
{
    __shared__ float sWe[EDD * HH];      // 32 KB
    __shared__ float sbe[HH];
    __shared__ float sattr[4][4 * EDD];  // [wave][edge-in-group][k]  4 KB

    for (int i = threadIdx.x; i < EDD * HH / 4; i += 256)
        reinterpret_cast<float4*>(sWe)[i] = reinterpret_cast<const float4*>(We)[i];
    if (threadIdx.x < HH) sbe[threadIdx.x] = be[threadIdx.x];
    __syncthreads();

    const int wave = threadIdx.x >> 6;
    const int lane = threadIdx.x & 63;
    const int c0 = lane * 2;
    const float bx = sbe[c0], by = sbe[c0 + 1];

    const int ngroups = (E + 3) >> 2;
    for (int g = blockIdx.x * 4 + wave; g < ngroups; g += gridDim.x * 4) {
        const int e0 = g * 4;
        float* sa = sattr[wave];
        #pragma unroll
        for (int j = 0; j < 4; ++j) {
            int e = e0 + j;
            if (e < E) sa[j * EDD + lane] = ea[(long long)e * EDD + lane];
        }
        float ax[4], ay[4];
        #pragma unroll
        for (int j = 0; j < 4; ++j) { ax[j] = bx; ay[j] = by; }

        #pragma unroll
        for (int k4 = 0; k4 < EDD; k4 += 4) {
            float4 a0 = *reinterpret_cast<const float4*>(&sa[0 * EDD + k4]);
            float4 a1 = *reinterpret_cast<const float4*>(&sa[1 * EDD + k4]);
            float4 a2 = *reinterpret_cast<const float4*>(&sa[2 * EDD + k4]);
            float4 a3 = *reinterpret_cast<const float4*>(&sa[3 * EDD + k4]);
            #pragma unroll
            for (int kk = 0; kk < 4; ++kk) {
                const float2 w = *reinterpret_cast<const float2*>(&sWe[(k4 + kk) * HH + c0]);
                const float f0 = (&a0.x)[kk];
                const float f1 = (&a1.x)[kk];
                const float f2 = (&a2.x)[kk];
                const float f3 = (&a3.x)[kk];
                ax[0] = fmaf(f0, w.x, ax[0]); ay[0] = fmaf(f0, w.y, ay[0]);
                ax[1] = fmaf(f1, w.x, ax[1]); ay[1] = fmaf(f1, w.y, ay[1]);
                ax[2] = fmaf(f2, w.x, ax[2]); ay[2] = fmaf(f2, w.y, ay[2]);
                ax[3] = fmaf(f3, w.x, ax[3]); ay[3] = fmaf(f3, w.y, ay[3]);
            }
        }

        #pragma unroll
        for (int j = 0; j < 4; ++j) {
            int e = e0 + j;
            if (e < E) {
                const int sj = src[e];
                const int dj = dst[e];
                const float2 sv = *reinterpret_cast<const float2*>(&s[(long long)sj * HH + c0]);
                const float mx = fmaxf(ax[j] + sv.x, 0.f);
                const float my = fmaxf(ay[j] + sv.y, 0.f);
                float* ap = &agg[(long long)dj * HH + c0];
                atomicAdd(ap, mx);
                atomicAdd(ap + 1, my);
            }
        }
    }
}

// ---------------------------------------------------------------------------
// Node MLP stage 1: t1 = silu((s + agg) @ W1 + b1), written in place of agg.
// Wave-per-node GEMV; W1 (64KB) in LDS; h broadcast via v_readlane.
// ---------------------------------------------------------------------------
__global__ __launch_bounds__(256) void gine_node1(
    const float* __restrict__ s,
    float* __restrict__ agg_t1,      // in: agg, out: t1 (same buffer)
    const float* __restrict__ W1,    // [HH][HH]
    const float* __restrict__ b1,    // [HH]
    int N)
{
    __shared__ float sW[HH * HH];    // 64 KB
    for (int i = threadIdx.x; i < HH * HH / 4; i += 256)
        reinterpret_cast<float4*>(sW)[i] = reinterpret_cast<const float4*>(W1)[i];
    __syncthreads();

    const int wave = threadIdx.x >> 6;
    const int lane = threadIdx.x & 63;
    const int c0 = 2 * lane;
    const float bx = b1[c0], by = b1[c0 + 1];

    for (int n = blockIdx.x * 4 + wave; n < N; n += gridDim.x * 4) {
        const float2 sv = *reinterpret_cast<const float2*>(&s[(long long)n * HH + c0]);
        const float2 av = *reinterpret_cast<const float2*>(&agg_t1[(long long)n * HH + c0]);
        const float hx = sv.x + av.x;
        const float hy = sv.y + av.y;
        float accx = bx, accy = by;
        #pragma unroll
        for (int m = 0; m < 64; ++m) {
            const float h0 = __uint_as_float(__builtin_amdgcn_readlane(__float_as_uint(hx), m));
            const float h1 = __uint_as_float(__builtin_amdgcn_readlane(__float_as_uint(hy), m));
            const float2 w0 = *reinterpret_cast<const float2*>(&sW[(2 * m) * HH + c0]);
            const float2 w1 = *reinterpret_cast<const float2*>(&sW[(2 * m + 1) * HH + c0]);
            accx = fmaf(h0, w0.x, accx); accy = fmaf(h0, w0.y, accy);
            accx = fmaf(h1, w1.x, accx); accy = fmaf(h1, w1.y, accy);
        }
        // silu
        accx = accx / (1.f + __expf(-accx));
        accy = accy / (1.f + __expf(-accy));
        *reinterpret_cast<float2*>(&agg_t1[(long long)n * HH + c0]) = make_float2(accx, accy);
    }
}

// ---------------------------------------------------------------------------
// Node MLP stage 2 + residual + LayerNorm + SiLU:
//   v = s + t1 @ W2 + b2 ; s_out = silu(LN(v) * gamma + beta)
// ---------------------------------------------------------------------------
__global__ __launch_bounds__(256) void gine_node2(
    const float* __restrict__ s_in,
    const float* __restrict__ t1,
    const float* __restrict__ W2,    // [HH][HH]
    const float* __restrict__ b2,    // [HH]
    const float* __restrict__ gamma,
    const float* __restrict__ beta,
    float* __restrict__ s_out,       // may alias s_in
    int N)
{
    __shared__ float sW[HH * HH];    // 64 KB
    for (int i = threadIdx.x; i < HH * HH / 4; i += 256)
        reinterpret_cast<float4*>(sW)[i] = reinterpret_cast<const float4*>(W2)[i];
    __syncthreads();

    const int wave = threadIdx.x >> 6;
    const int lane = threadIdx.x & 63;
    const int c0 = 2 * lane;
    const float bx = b2[c0], by = b2[c0 + 1];
    const float gx = gamma[c0], gy = gamma[c0 + 1];
    const float ex = beta[c0], ey = beta[c0 + 1];

    for (int n = blockIdx.x * 4 + wave; n < N; n += gridDim.x * 4) {
        const float2 tv = *reinterpret_cast<const float2*>(&t1[(long long)n * HH + c0]);
        float accx = bx, accy = by;
        #pragma unroll
        for (int m = 0; m < 64; ++m) {
            const float h0 = __uint_as_float(__builtin_amdgcn_readlane(__float_as_uint(tv.x), m));
            const float h1 = __uint_as_float(__builtin_amdgcn_readlane(__float_as_uint(tv.y), m));
            const float2 w0 = *reinterpret_cast<const float2*>(&sW[(2 * m) * HH + c0]);
            const float2 w1 = *reinterpret_cast<const float2*>(&sW[(2 * m + 1) * HH + c0]);
            accx = fmaf(h0, w0.x, accx); accy = fmaf(h0, w0.y, accy);
            accx = fmaf(h1, w1.x, accx); accy = fmaf(h1, w1.y, accy);
        }
        const float2 sv = *reinterpret_cast<const float2*>(&s_in[(long long)n * HH + c0]);
        const float vx = sv.x + accx;
        const float vy = sv.y + accy;

        // LayerNorm across 128 channels (2 per lane, 64 lanes)
        float sum = vx + vy;
        float ssq = vx * vx + vy * vy;
        #pragma unroll
        for (int off = 32; off > 0; off >>= 1) {
            sum += __shfl_xor(sum, off, 64);
            ssq += __shfl_xor(ssq, off, 64);
        }
        const float mu = sum * (1.0f / HH);
        const float var = ssq * (1.0f / HH) - mu * mu;
        const float rs = rsqrtf(var + LN_EPS);

        float ox = (vx - mu) * rs * gx + ex;
        float oy = (vy - mu) * rs * gy + ey;
        ox = ox / (1.f + __expf(-ox));
        oy = oy / (1.f + __expf(-oy));
        *reinterpret_cast<float2*>(&s_out[(long long)n * HH + c0]) = make_float2(ox, oy);
    }
}

// ---------------------------------------------------------------------------
extern "C" void kernel_launch(void* const* d_in, const int* in_sizes, int n_in,
                              void* d_out, int out_size, void* d_ws, size_t ws_size,
                              hipStream_t stream) {
    const float* s0  = (const float*)d_in[0];
    const int*   ei  = (const int*)  d_in[1];
    const float* ea  = (const float*)d_in[2];
    const float* We  = (const float*)d_in[3];
    const float* be  = (const float*)d_in[4];
    const float* W1  = (const float*)d_in[5];
    const float* b1  = (const float*)d_in[6];
    const float* W2  = (const float*)d_in[7];
    const float* b2  = (const float*)d_in[8];
    const float* gm  = (const float*)d_in[9];
    const float* bt  = (const float*)d_in[10];

    const int NH = in_sizes[0];          // N * 128
    const int N  = NH / HH;
    const int E  = in_sizes[1] / 2;
    const int* src = ei;                 // edge_index[0]
    const int* dst = ei + E;             // edge_index[1]

    float* sbuf = (float*)d_ws;          // [N,H] working node state
    float* aggb = sbuf + NH;             // [N,H] agg, reused in-place as t1

    hipMemcpyAsync(sbuf, s0, sizeof(float) * NH, hipMemcpyDeviceToDevice, stream);

    for (int l = 0; l < NLAYER; ++l) {
        hipMemsetAsync(aggb, 0, sizeof(float) * NH, stream);
        gine_edge<<<1024, 256, 0, stream>>>(sbuf, src, dst, ea,
                                            We + (long long)l * EDD * HH,
                                            be + l * HH, aggb, E);
        gine_node1<<<512, 256, 0, stream>>>(sbuf, aggb,
                                            W1 + (long long)l * HH * HH,
                                            b1 + l * HH, N);
        float* out = (l == NLAYER - 1) ? (float*)d_out : sbuf;
        gine_node2<<<512, 256, 0, stream>>>(sbuf, aggb,
                                            W2 + (long long)l * HH * HH,
                                            b2 + l * HH,
                                            gm + l * HH, bt + l * HH,
                                            out, N);
    }
}

// Round 4
// 3381.105 us; speedup vs baseline: 1.0166x; 1.0166x over previous
//
#include <hip/hip_runtime.h>
#include <hip/hip_bf16.h>

#define HH 128   // hidden
#define EDD 64   // edge_dim
#define NLAYER 3
#define LN_EPS 1e-5f

// ---------------------------------------------------------------------------
// CSR build (once per call; edge_index is layer-invariant)
// ---------------------------------------------------------------------------
__global__ __launch_bounds__(256) void hist_kernel(
    const int* __restrict__ dst, int* __restrict__ cnt, int E)
{
    for (int e = blockIdx.x * blockDim.x + threadIdx.x; e < E;
         e += gridDim.x * blockDim.x)
        atomicAdd(&cnt[dst[e]], 1);
}

// single-block exclusive scan over cnt[0..N) -> off[0..N]
__global__ __launch_bounds__(1024) void scan_kernel(
    const int* __restrict__ cnt, int* __restrict__ off, int N)
{
    __shared__ int ls[1024];
    const int t = threadIdx.x;
    const int C = (N + 1023) >> 10;
    const int lo = t * C;
    const int hi = min(lo + C, N);
    int sum = 0;
    for (int i = lo; i < hi; ++i) sum += cnt[i];
    ls[t] = sum;
    __syncthreads();
    #pragma unroll
    for (int d = 1; d < 1024; d <<= 1) {
        int v = (t >= d) ? ls[t - d] : 0;
        __syncthreads();
        ls[t] += v;
        __syncthreads();
    }
    int excl = (t == 0) ? 0 : ls[t - 1];
    for (int i = lo; i < hi; ++i) { off[i] = excl; excl += cnt[i]; }
    if (t == 1023) off[N] = ls[1023];
}

__global__ __launch_bounds__(256) void scatter_kernel(
    const int* __restrict__ src, const int* __restrict__ dst,
    int* __restrict__ cursor, int2* __restrict__ perm2, int E)
{
    for (int e = blockIdx.x * blockDim.x + threadIdx.x; e < E;
         e += gridDim.x * blockDim.x) {
        const int pos = atomicAdd(&cursor[dst[e]], 1);
        perm2[pos] = make_int2(src[e], e);
    }
}

// ---------------------------------------------------------------------------
// Gather-only aggregation: wave per node, walk CSR edge list in chunks of 4.
//   h[n] = s[n] + sum_{e in in(n)} relu(s[src_e] + ea[e]@We + be)
// We (32KB) in LDS; ea rows staged in wave-private LDS (no barrier needed).
// No atomics, coalesced single write per node row.
// ---------------------------------------------------------------------------
__global__ __launch_bounds__(256) void gine_agg(
    const float* __restrict__ s,
    const int2* __restrict__ perm2,   // (src, edge_id) sorted by dst
    const int* __restrict__ off,      // [N+1]
    const float* __restrict__ ea,
    const float* __restrict__ We,     // [EDD][HH] this layer
    const float* __restrict__ be,     // [HH]
    float* __restrict__ hbuf,         // out: s + agg
    int N)
{
    __shared__ float sWe[EDD * HH];      // 32 KB
    __shared__ float sbe[HH];
    __shared__ float sattr[4][4 * EDD];  // [wave][edge-in-chunk][k]  4 KB

    for (int i = threadIdx.x; i < EDD * HH / 4; i += 256)
        reinterpret_cast<float4*>(sWe)[i] = reinterpret_cast<const float4*>(We)[i];
    if (threadIdx.x < HH) sbe[threadIdx.x] = be[threadIdx.x];
    __syncthreads();

    const int wave = threadIdx.x >> 6;
    const int lane = threadIdx.x & 63;
    const int c0 = lane * 2;
    const float bx = sbe[c0], by = sbe[c0 + 1];
    float* sa = sattr[wave];

    for (int n = blockIdx.x * 4 + wave; n < N; n += gridDim.x * 4) {
        const int p0 = off[n];
        const int p1 = off[n + 1];
        float accx = 0.f, accy = 0.f;

        for (int p = p0; p < p1; p += 4) {
            const int m = min(4, p1 - p);
            int2 pe[4];
            #pragma unroll
            for (int j = 0; j < 4; ++j) {
                if (j < m) {
                    pe[j] = perm2[p + j];
                    sa[j * EDD + lane] = ea[(long long)pe[j].y * EDD + lane];
                }
            }
            float ax[4], ay[4];
            #pragma unroll
            for (int j = 0; j < 4; ++j) { ax[j] = bx; ay[j] = by; }

            #pragma unroll
            for (int k4 = 0; k4 < EDD; k4 += 4) {
                float4 a0 = *reinterpret_cast<const float4*>(&sa[0 * EDD + k4]);
                float4 a1 = *reinterpret_cast<const float4*>(&sa[1 * EDD + k4]);
                float4 a2 = *reinterpret_cast<const float4*>(&sa[2 * EDD + k4]);
                float4 a3 = *reinterpret_cast<const float4*>(&sa[3 * EDD + k4]);
                #pragma unroll
                for (int kk = 0; kk < 4; ++kk) {
                    const float2 w = *reinterpret_cast<const float2*>(&sWe[(k4 + kk) * HH + c0]);
                    const float f0 = (&a0.x)[kk];
                    const float f1 = (&a1.x)[kk];
                    const float f2 = (&a2.x)[kk];
                    const float f3 = (&a3.x)[kk];
                    ax[0] = fmaf(f0, w.x, ax[0]); ay[0] = fmaf(f0, w.y, ay[0]);
                    ax[1] = fmaf(f1, w.x, ax[1]); ay[1] = fmaf(f1, w.y, ay[1]);
                    ax[2] = fmaf(f2, w.x, ax[2]); ay[2] = fmaf(f2, w.y, ay[2]);
                    ax[3] = fmaf(f3, w.x, ax[3]); ay[3] = fmaf(f3, w.y, ay[3]);
                }
            }

            #pragma unroll
            for (int j = 0; j < 4; ++j) {
                if (j < m) {
                    const float2 sv = *reinterpret_cast<const float2*>(
                        &s[(long long)pe[j].x * HH + c0]);
                    accx += fmaxf(ax[j] + sv.x, 0.f);
                    accy += fmaxf(ay[j] + sv.y, 0.f);
                }
            }
        }

        const float2 sv = *reinterpret_cast<const float2*>(&s[(long long)n * HH + c0]);
        *reinterpret_cast<float2*>(&hbuf[(long long)n * HH + c0]) =
            make_float2(sv.x + accx, sv.y + accy);
    }
}

// ---------------------------------------------------------------------------
// Node MLP stage 1 (in place): h -> silu(h @ W1 + b1)
// ---------------------------------------------------------------------------
__global__ __launch_bounds__(256) void gine_node1(
    float* __restrict__ h_t1,        // in: h = s+agg, out: t1 (same buffer)
    const float* __restrict__ W1,    // [HH][HH]
    const float* __restrict__ b1,    // [HH]
    int N)
{
    __shared__ float sW[HH * HH];    // 64 KB
    for (int i = threadIdx.x; i < HH * HH / 4; i += 256)
        reinterpret_cast<float4*>(sW)[i] = reinterpret_cast<const float4*>(W1)[i];
    __syncthreads();

    const int wave = threadIdx.x >> 6;
    const int lane = threadIdx.x & 63;
    const int c0 = 2 * lane;
    const float bx = b1[c0], by = b1[c0 + 1];

    for (int n = blockIdx.x * 4 + wave; n < N; n += gridDim.x * 4) {
        const float2 hv = *reinterpret_cast<const float2*>(&h_t1[(long long)n * HH + c0]);
        float accx = bx, accy = by;
        #pragma unroll
        for (int m = 0; m < 64; ++m) {
            const float h0 = __uint_as_float(__builtin_amdgcn_readlane(__float_as_uint(hv.x), m));
            const float h1 = __uint_as_float(__builtin_amdgcn_readlane(__float_as_uint(hv.y), m));
            const float2 w0 = *reinterpret_cast<const float2*>(&sW[(2 * m) * HH + c0]);
            const float2 w1 = *reinterpret_cast<const float2*>(&sW[(2 * m + 1) * HH + c0]);
            accx = fmaf(h0, w0.x, accx); accy = fmaf(h0, w0.y, accy);
            accx = fmaf(h1, w1.x, accx); accy = fmaf(h1, w1.y, accy);
        }
        accx = accx / (1.f + __expf(-accx));
        accy = accy / (1.f + __expf(-accy));
        *reinterpret_cast<float2*>(&h_t1[(long long)n * HH + c0]) = make_float2(accx, accy);
    }
}

// ---------------------------------------------------------------------------
// Node MLP stage 2 + residual + LayerNorm + SiLU
// ---------------------------------------------------------------------------
__global__ __launch_bounds__(256) void gine_node2(
    const float* __restrict__ s_in,
    const float* __restrict__ t1,
    const float* __restrict__ W2,    // [HH][HH]
    const float* __restrict__ b2,
    const float* __restrict__ gamma,
    const float* __restrict__ beta,
    float* __restrict__ s_out,       // may alias s_in
    int N)
{
    __shared__ float sW[HH * HH];    // 64 KB
    for (int i = threadIdx.x; i < HH * HH / 4; i += 256)
        reinterpret_cast<float4*>(sW)[i] = reinterpret_cast<const float4*>(W2)[i];
    __syncthreads();

    const int wave = threadIdx.x >> 6;
    const int lane = threadIdx.x & 63;
    const int c0 = 2 * lane;
    const float bx = b2[c0], by = b2[c0 + 1];
    const float gx = gamma[c0], gy = gamma[c0 + 1];
    const float ex = beta[c0], ey = beta[c0 + 1];

    for (int n = blockIdx.x * 4 + wave; n < N; n += gridDim.x * 4) {
        const float2 tv = *reinterpret_cast<const float2*>(&t1[(long long)n * HH + c0]);
        float accx = bx, accy = by;
        #pragma unroll
        for (int m = 0; m < 64; ++m) {
            const float h0 = __uint_as_float(__builtin_amdgcn_readlane(__float_as_uint(tv.x), m));
            const float h1 = __uint_as_float(__builtin_amdgcn_readlane(__float_as_uint(tv.y), m));
            const float2 w0 = *reinterpret_cast<const float2*>(&sW[(2 * m) * HH + c0]);
            const float2 w1 = *reinterpret_cast<const float2*>(&sW[(2 * m + 1) * HH + c0]);
            accx = fmaf(h0, w0.x, accx); accy = fmaf(h0, w0.y, accy);
            accx = fmaf(h1, w1.x, accx); accy = fmaf(h1, w1.y, accy);
        }
        const float2 sv = *reinterpret_cast<const float2*>(&s_in[(long long)n * HH + c0]);
        const float vx = sv.x + accx;
        const float vy = sv.y + accy;

        float sum = vx + vy;
        float ssq = vx * vx + vy * vy;
        #pragma unroll
        for (int off = 32; off > 0; off >>= 1) {
            sum += __shfl_xor(sum, off, 64);
            ssq += __shfl_xor(ssq, off, 64);
        }
        const float mu = sum * (1.0f / HH);
        const float var = ssq * (1.0f / HH) - mu * mu;
        const float rs = rsqrtf(var + LN_EPS);

        float ox = (vx - mu) * rs * gx + ex;
        float oy = (vy - mu) * rs * gy + ey;
        ox = ox / (1.f + __expf(-ox));
        oy = oy / (1.f + __expf(-oy));
        *reinterpret_cast<float2*>(&s_out[(long long)n * HH + c0]) = make_float2(ox, oy);
    }
}

// ---------------------------------------------------------------------------
extern "C" void kernel_launch(void* const* d_in, const int* in_sizes, int n_in,
                              void* d_out, int out_size, void* d_ws, size_t ws_size,
                              hipStream_t stream) {
    const float* s0  = (const float*)d_in[0];
    const int*   ei  = (const int*)  d_in[1];
    const float* ea  = (const float*)d_in[2];
    const float* We  = (const float*)d_in[3];
    const float* be  = (const float*)d_in[4];
    const float* W1  = (const float*)d_in[5];
    const float* b1  = (const float*)d_in[6];
    const float* W2  = (const float*)d_in[7];
    const float* b2  = (const float*)d_in[8];
    const float* gm  = (const float*)d_in[9];
    const float* bt  = (const float*)d_in[10];

    const int NH = in_sizes[0];          // N * 128
    const int N  = NH / HH;
    const int E  = in_sizes[1] / 2;
    const int* src = ei;                 // edge_index[0]
    const int* dst = ei + E;             // edge_index[1]

    // ws layout
    float* sbuf   = (float*)d_ws;            // [N*H] working node state
    float* hbuf   = sbuf + NH;               // [N*H] h = s+agg, reused as t1
    int2*  perm2  = (int2*)(hbuf + NH);      // [E] (src, edge_id) sorted by dst
    int*   off    = (int*)(perm2 + E);       // [N+1]
    int*   cursor = off + (N + 1);           // [N]
    int*   cnt    = cursor + N;              // [N]

    hipMemcpyAsync(sbuf, s0, sizeof(float) * NH, hipMemcpyDeviceToDevice, stream);

    // Build dst-sorted CSR once (edge_index is layer-invariant)
    hipMemsetAsync(cnt, 0, sizeof(int) * N, stream);
    hist_kernel<<<1024, 256, 0, stream>>>(dst, cnt, E);
    scan_kernel<<<1, 1024, 0, stream>>>(cnt, off, N);
    hipMemcpyAsync(cursor, off, sizeof(int) * N, hipMemcpyDeviceToDevice, stream);
    scatter_kernel<<<1024, 256, 0, stream>>>(src, dst, cursor, perm2, E);

    for (int l = 0; l < NLAYER; ++l) {
        gine_agg<<<1024, 256, 0, stream>>>(sbuf, perm2, off, ea,
                                           We + (long long)l * EDD * HH,
                                           be + l * HH, hbuf, N);
        gine_node1<<<512, 256, 0, stream>>>(hbuf,
                                            W1 + (long long)l * HH * HH,
                                            b1 + l * HH, N);
        float* out = (l == NLAYER - 1) ? (float*)d_out : sbuf;
        gine_node2<<<512, 256, 0, stream>>>(sbuf, hbuf,
                                            W2 + (long long)l * HH * HH,
                                            b2 + l * HH,
                                            gm + l * HH, bt + l * HH,
                                            out, N);
    }
}

// Round 5
// 1218.293 us; speedup vs baseline: 2.8215x; 2.7753x over previous
//
#include <hip/hip_runtime.h>
#include <hip/hip_bf16.h>

#define HH 128   // hidden
#define EDD 64   // edge_dim
#define NLAYER 3
#define LN_EPS 1e-5f

typedef __attribute__((ext_vector_type(8))) __bf16 bf16x8;
typedef __attribute__((ext_vector_type(4))) float f32x4;

// ---------------------------------------------------------------------------
// CSR build (once per call; edge_index is layer-invariant)
// ---------------------------------------------------------------------------
__global__ __launch_bounds__(256) void hist_kernel(
    const int* __restrict__ dst, int* __restrict__ cnt, int E)
{
    for (int e = blockIdx.x * blockDim.x + threadIdx.x; e < E;
         e += gridDim.x * blockDim.x)
        atomicAdd(&cnt[dst[e]], 1);
}

__global__ __launch_bounds__(1024) void scan_kernel(
    const int* __restrict__ cnt, int* __restrict__ off, int N)
{
    __shared__ int ls[1024];
    const int t = threadIdx.x;
    const int C = (N + 1023) >> 10;
    const int lo = t * C;
    const int hi = min(lo + C, N);
    int sum = 0;
    for (int i = lo; i < hi; ++i) sum += cnt[i];
    ls[t] = sum;
    __syncthreads();
    for (int d = 1; d < 1024; d <<= 1) {
        int v = (t >= d) ? ls[t - d] : 0;
        __syncthreads();
        ls[t] += v;
        __syncthreads();
    }
    int excl = (t == 0) ? 0 : ls[t - 1];
    for (int i = lo; i < hi; ++i) { off[i] = excl; excl += cnt[i]; }
    if (t == 1023) off[N] = ls[1023];
}

__global__ __launch_bounds__(256) void scatter2_kernel(
    const int* __restrict__ src, const int* __restrict__ dst,
    int* __restrict__ cursor, int* __restrict__ src_s,
    int* __restrict__ eid, int E)
{
    for (int e = blockIdx.x * blockDim.x + threadIdx.x; e < E;
         e += gridDim.x * blockDim.x) {
        const int pos = atomicAdd(&cursor[dst[e]], 1);
        src_s[pos] = src[e];
        eid[pos]   = e;
    }
}

// ---------------------------------------------------------------------------
// Reorder edge_attr into dst-sorted order, converted to bf16 row-major [p][64]
// ---------------------------------------------------------------------------
__global__ __launch_bounds__(256) void prep_ea(
    const float* __restrict__ ea, const int* __restrict__ eid,
    unsigned short* __restrict__ ea_b, int E)
{
    const int k = threadIdx.x & 63;
    for (int p = blockIdx.x * 4 + (threadIdx.x >> 6); p < E; p += gridDim.x * 4) {
        const int e = eid[p];
        const float v = ea[(long long)e * EDD + k];
        ea_b[(long long)p * EDD + k] = __builtin_bit_cast(unsigned short, (__bf16)v);
    }
}

// ---------------------------------------------------------------------------
// We -> bf16 B-fragments for mfma_f32_16x16x32_bf16.
// WeB[layer][kt*8+ct][lane] holds 8 bf16: B[k = kt*32 + (lane>>4)*8 + j]
//                                         [col = ct*16 + (lane&15)]
// ---------------------------------------------------------------------------
__global__ void prep_we(const float* __restrict__ We, bf16x8* __restrict__ WeB)
{
    const int t = blockIdx.x * blockDim.x + threadIdx.x;
    if (t >= NLAYER * 16 * 64) return;
    const int lane  = t & 63;
    const int frag  = (t >> 6) & 15;
    const int layer = t >> 10;
    const int kt = frag >> 3, ct = frag & 7;
    const int col = ct * 16 + (lane & 15);
    const int k0  = kt * 32 + (lane >> 4) * 8;
    bf16x8 v;
    #pragma unroll
    for (int j = 0; j < 8; ++j)
        v[j] = (__bf16)We[(long long)layer * EDD * HH + (k0 + j) * HH + col];
    WeB[t] = v;
}

// ---------------------------------------------------------------------------
// MFMA aggregation: block per node (grid-stride), 4 waves split 8 col-tiles.
// Per 16-edge chunk: A = bf16 attr rows (row=lane&15, k=(lane>>4)*8+j),
// 4 MFMA vs register-resident We frags, then relu(s[src]+e+be) masked-sum.
// C/D layout (verified m89): col=lane&15, row=(lane>>4)*4+reg.
// No LDS; We never re-read from memory.
// ---------------------------------------------------------------------------
__global__ __launch_bounds__(256) void gine_agg_mfma(
    const float* __restrict__ s,
    const int* __restrict__ src_s,    // dst-sorted src ids, padded
    const int* __restrict__ off,      // [N+1]
    const unsigned short* __restrict__ ea_b,  // [E+16][64] bf16, padded
    const bf16x8* __restrict__ WeB,   // this layer's 16 frags
    const float* __restrict__ be,
    float* __restrict__ hbuf,         // out: s + agg
    int N)
{
    const int wave = threadIdx.x >> 6;   // col-tiles {2*wave, 2*wave+1}
    const int lane = threadIdx.x & 63;
    const int lmod = lane & 15;
    const int ldiv = lane >> 4;

    const bf16x8 wb00 = WeB[(0 * 8 + 2 * wave    ) * 64 + lane];
    const bf16x8 wb01 = WeB[(0 * 8 + 2 * wave + 1) * 64 + lane];
    const bf16x8 wb10 = WeB[(1 * 8 + 2 * wave    ) * 64 + lane];
    const bf16x8 wb11 = WeB[(1 * 8 + 2 * wave + 1) * 64 + lane];

    const int col0 = (2 * wave)     * 16 + lmod;
    const int col1 = (2 * wave + 1) * 16 + lmod;
    const float bev0 = be[col0];
    const float bev1 = be[col1];

    for (int n = blockIdx.x; n < N; n += gridDim.x) {
        const int p0 = off[n], p1 = off[n + 1];
        float acc0 = 0.f, acc1 = 0.f;

        for (int p = p0; p < p1; p += 16) {
            const int rem = p1 - p;
            const unsigned short* arow =
                ea_b + (long long)(p + lmod) * EDD + ldiv * 8;
            const bf16x8 a0 = *reinterpret_cast<const bf16x8*>(arow);
            const bf16x8 a1 = *reinterpret_cast<const bf16x8*>(arow + 32);

            const int ms0 = src_s[p + ldiv * 4 + 0];
            const int ms1 = src_s[p + ldiv * 4 + 1];
            const int ms2 = src_s[p + ldiv * 4 + 2];
            const int ms3 = src_s[p + ldiv * 4 + 3];

            f32x4 c0 = {0.f, 0.f, 0.f, 0.f};
            f32x4 c1 = {0.f, 0.f, 0.f, 0.f};
            c0 = __builtin_amdgcn_mfma_f32_16x16x32_bf16(a0, wb00, c0, 0, 0, 0);
            c0 = __builtin_amdgcn_mfma_f32_16x16x32_bf16(a1, wb10, c0, 0, 0, 0);
            c1 = __builtin_amdgcn_mfma_f32_16x16x32_bf16(a0, wb01, c1, 0, 0, 0);
            c1 = __builtin_amdgcn_mfma_f32_16x16x32_bf16(a1, wb11, c1, 0, 0, 0);

            const int base_row = ldiv * 4;
            const int msv[4] = {ms0, ms1, ms2, ms3};
            #pragma unroll
            for (int r = 0; r < 4; ++r) {
                if (base_row + r < rem) {
                    const long long srow = (long long)msv[r] * HH;
                    const float sv0 = s[srow + col0];
                    const float sv1 = s[srow + col1];
                    acc0 += fmaxf(sv0 + c0[r] + bev0, 0.f);
                    acc1 += fmaxf(sv1 + c1[r] + bev1, 0.f);
                }
            }
        }

        // reduce over the 4 row-groups (lanes xor 16, 32)
        acc0 += __shfl_xor(acc0, 16, 64);
        acc0 += __shfl_xor(acc0, 32, 64);
        acc1 += __shfl_xor(acc1, 16, 64);
        acc1 += __shfl_xor(acc1, 32, 64);

        if (ldiv < 2) {
            const int col = (ldiv == 0) ? col0 : col1;
            const float a = (ldiv == 0) ? acc0 : acc1;
            hbuf[(long long)n * HH + col] = s[(long long)n * HH + col] + a;
        }
    }
}

// ---------------------------------------------------------------------------
// Node MLP stage 1 (in place): h -> silu(h @ W1 + b1)
// ---------------------------------------------------------------------------
__global__ __launch_bounds__(256) void gine_node1(
    float* __restrict__ h_t1,
    const float* __restrict__ W1,
    const float* __restrict__ b1,
    int N)
{
    __shared__ float sW[HH * HH];
    for (int i = threadIdx.x; i < HH * HH / 4; i += 256)
        reinterpret_cast<float4*>(sW)[i] = reinterpret_cast<const float4*>(W1)[i];
    __syncthreads();

    const int wave = threadIdx.x >> 6;
    const int lane = threadIdx.x & 63;
    const int c0 = 2 * lane;
    const float bx = b1[c0], by = b1[c0 + 1];

    for (int n = blockIdx.x * 4 + wave; n < N; n += gridDim.x * 4) {
        const float2 hv = *reinterpret_cast<const float2*>(&h_t1[(long long)n * HH + c0]);
        float accx = bx, accy = by;
        #pragma unroll
        for (int m = 0; m < 64; ++m) {
            const float h0 = __uint_as_float(__builtin_amdgcn_readlane(__float_as_uint(hv.x), m));
            const float h1 = __uint_as_float(__builtin_amdgcn_readlane(__float_as_uint(hv.y), m));
            const float2 w0 = *reinterpret_cast<const float2*>(&sW[(2 * m) * HH + c0]);
            const float2 w1 = *reinterpret_cast<const float2*>(&sW[(2 * m + 1) * HH + c0]);
            accx = fmaf(h0, w0.x, accx); accy = fmaf(h0, w0.y, accy);
            accx = fmaf(h1, w1.x, accx); accy = fmaf(h1, w1.y, accy);
        }
        accx = accx / (1.f + __expf(-accx));
        accy = accy / (1.f + __expf(-accy));
        *reinterpret_cast<float2*>(&h_t1[(long long)n * HH + c0]) = make_float2(accx, accy);
    }
}

// ---------------------------------------------------------------------------
// Node MLP stage 2 + residual + LayerNorm + SiLU
// ---------------------------------------------------------------------------
__global__ __launch_bounds__(256) void gine_node2(
    const float* __restrict__ s_in,
    const float* __restrict__ t1,
    const float* __restrict__ W2,
    const float* __restrict__ b2,
    const float* __restrict__ gamma,
    const float* __restrict__ beta,
    float* __restrict__ s_out,
    int N)
{
    __shared__ float sW[HH * HH];
    for (int i = threadIdx.x; i < HH * HH / 4; i += 256)
        reinterpret_cast<float4*>(sW)[i] = reinterpret_cast<const float4*>(W2)[i];
    __syncthreads();

    const int wave = threadIdx.x >> 6;
    const int lane = threadIdx.x & 63;
    const int c0 = 2 * lane;
    const float bx = b2[c0], by = b2[c0 + 1];
    const float gx = gamma[c0], gy = gamma[c0 + 1];
    const float ex = beta[c0], ey = beta[c0 + 1];

    for (int n = blockIdx.x * 4 + wave; n < N; n += gridDim.x * 4) {
        const float2 tv = *reinterpret_cast<const float2*>(&t1[(long long)n * HH + c0]);
        float accx = bx, accy = by;
        #pragma unroll
        for (int m = 0; m < 64; ++m) {
            const float h0 = __uint_as_float(__builtin_amdgcn_readlane(__float_as_uint(tv.x), m));
            const float h1 = __uint_as_float(__builtin_amdgcn_readlane(__float_as_uint(tv.y), m));
            const float2 w0 = *reinterpret_cast<const float2*>(&sW[(2 * m) * HH + c0]);
            const float2 w1 = *reinterpret_cast<const float2*>(&sW[(2 * m + 1) * HH + c0]);
            accx = fmaf(h0, w0.x, accx); accy = fmaf(h0, w0.y, accy);
            accx = fmaf(h1, w1.x, accx); accy = fmaf(h1, w1.y, accy);
        }
        const float2 sv = *reinterpret_cast<const float2*>(&s_in[(long long)n * HH + c0]);
        const float vx = sv.x + accx;
        const float vy = sv.y + accy;

        float sum = vx + vy;
        float ssq = vx * vx + vy * vy;
        #pragma unroll
        for (int o = 32; o > 0; o >>= 1) {
            sum += __shfl_xor(sum, o, 64);
            ssq += __shfl_xor(ssq, o, 64);
        }
        const float mu = sum * (1.0f / HH);
        const float var = ssq * (1.0f / HH) - mu * mu;
        const float rs = rsqrtf(var + LN_EPS);

        float ox = (vx - mu) * rs * gx + ex;
        float oy = (vy - mu) * rs * gy + ey;
        ox = ox / (1.f + __expf(-ox));
        oy = oy / (1.f + __expf(-oy));
        *reinterpret_cast<float2*>(&s_out[(long long)n * HH + c0]) = make_float2(ox, oy);
    }
}

// ---------------------------------------------------------------------------
extern "C" void kernel_launch(void* const* d_in, const int* in_sizes, int n_in,
                              void* d_out, int out_size, void* d_ws, size_t ws_size,
                              hipStream_t stream) {
    const float* s0  = (const float*)d_in[0];
    const int*   ei  = (const int*)  d_in[1];
    const float* ea  = (const float*)d_in[2];
    const float* We  = (const float*)d_in[3];
    const float* be  = (const float*)d_in[4];
    const float* W1  = (const float*)d_in[5];
    const float* b1  = (const float*)d_in[6];
    const float* W2  = (const float*)d_in[7];
    const float* b2  = (const float*)d_in[8];
    const float* gm  = (const float*)d_in[9];
    const float* bt  = (const float*)d_in[10];

    const int NH = in_sizes[0];          // N * 128
    const int N  = NH / HH;
    const int E  = in_sizes[1] / 2;
    const int* src = ei;                 // edge_index[0]
    const int* dst = ei + E;             // edge_index[1]

    // ws layout (~161 MB total)
    float*          sbuf  = (float*)d_ws;                       // [N*H]
    float*          hbuf  = sbuf + NH;                          // [N*H]
    unsigned short* ea_b  = (unsigned short*)(hbuf + NH);       // [(E+16)*64] bf16
    bf16x8*         WeB   = (bf16x8*)(ea_b + (size_t)(E + 16) * EDD); // [3*16*64]
    int*            src_s = (int*)(WeB + NLAYER * 16 * 64);     // [E+16]
    int*            eid   = src_s + (E + 16);                   // [E]
    int*            off   = eid + E;                            // [N+1]
    int*            cursor= off + (N + 1);                      // [N]
    int*            cnt   = cursor + N;                         // [N]

    hipMemcpyAsync(sbuf, s0, sizeof(float) * NH, hipMemcpyDeviceToDevice, stream);

    // ---- one-time preprocessing (edge_index / edge_attr are layer-invariant)
    hipMemsetAsync(cnt, 0, sizeof(int) * N, stream);
    hist_kernel<<<1024, 256, 0, stream>>>(dst, cnt, E);
    scan_kernel<<<1, 1024, 0, stream>>>(cnt, off, N);
    hipMemcpyAsync(cursor, off, sizeof(int) * N, hipMemcpyDeviceToDevice, stream);
    scatter2_kernel<<<1024, 256, 0, stream>>>(src, dst, cursor, src_s, eid, E);
    hipMemsetAsync(ea_b + (size_t)E * EDD, 0, 16 * EDD * sizeof(unsigned short), stream);
    hipMemsetAsync(src_s + E, 0, 16 * sizeof(int), stream);
    prep_ea<<<2048, 256, 0, stream>>>(ea, eid, ea_b, E);
    prep_we<<<12, 256, 0, stream>>>(We, WeB);

    for (int l = 0; l < NLAYER; ++l) {
        gine_agg_mfma<<<4096, 256, 0, stream>>>(sbuf, src_s, off, ea_b,
                                                WeB + (size_t)l * 16 * 64,
                                                be + l * HH, hbuf, N);
        gine_node1<<<512, 256, 0, stream>>>(hbuf,
                                            W1 + (long long)l * HH * HH,
                                            b1 + l * HH, N);
        float* out = (l == NLAYER - 1) ? (float*)d_out : sbuf;
        gine_node2<<<512, 256, 0, stream>>>(sbuf, hbuf,
                                            W2 + (long long)l * HH * HH,
                                            b2 + l * HH,
                                            gm + l * HH, bt + l * HH,
                                            out, N);
    }
}

// Round 6
// 1187.972 us; speedup vs baseline: 2.8935x; 1.0255x over previous
//
#include <hip/hip_runtime.h>
#include <hip/hip_bf16.h>

#define HH 128   // hidden
#define EDD 64   // edge_dim
#define NLAYER 3
#define LN_EPS 1e-5f

typedef __attribute__((ext_vector_type(8))) __bf16 bf16x8;
typedef __attribute__((ext_vector_type(4))) float f32x4;

// ---------------------------------------------------------------------------
// CSR build (once per call; edge_index is layer-invariant)
// ---------------------------------------------------------------------------
__global__ __launch_bounds__(256) void hist_kernel(
    const int* __restrict__ dst, int* __restrict__ cnt, int E)
{
    for (int e = blockIdx.x * blockDim.x + threadIdx.x; e < E;
         e += gridDim.x * blockDim.x)
        atomicAdd(&cnt[dst[e]], 1);
}

__global__ __launch_bounds__(1024) void scan_kernel(
    const int* __restrict__ cnt, int* __restrict__ off, int N)
{
    __shared__ int ls[1024];
    const int t = threadIdx.x;
    const int C = (N + 1023) >> 10;
    const int lo = t * C;
    const int hi = min(lo + C, N);
    int sum = 0;
    for (int i = lo; i < hi; ++i) sum += cnt[i];
    ls[t] = sum;
    __syncthreads();
    for (int d = 1; d < 1024; d <<= 1) {
        int v = (t >= d) ? ls[t - d] : 0;
        __syncthreads();
        ls[t] += v;
        __syncthreads();
    }
    int excl = (t == 0) ? 0 : ls[t - 1];
    for (int i = lo; i < hi; ++i) { off[i] = excl; excl += cnt[i]; }
    if (t == 1023) off[N] = ls[1023];
}

__global__ __launch_bounds__(256) void scatter2_kernel(
    const int* __restrict__ src, const int* __restrict__ dst,
    int* __restrict__ cursor, int* __restrict__ src_s,
    int* __restrict__ eid_s, int E)
{
    for (int e = blockIdx.x * blockDim.x + threadIdx.x; e < E;
         e += gridDim.x * blockDim.x) {
        const int pos = atomicAdd(&cursor[dst[e]], 1);
        src_s[pos] = src[e];
        eid_s[pos] = e;
    }
}

// ---------------------------------------------------------------------------
// Streaming f32 -> bf16 convert of edge_attr, ORIGINAL edge order (coalesced
// both sides; no gather). Permutation is applied at A-load time in agg.
// ---------------------------------------------------------------------------
__global__ __launch_bounds__(256) void conv_ea(
    const float* __restrict__ ea, unsigned short* __restrict__ ea_b,
    long long total4)   // total elements / 4
{
    for (long long i = blockIdx.x * 256LL + threadIdx.x; i < total4;
         i += gridDim.x * 256LL) {
        const float4 v = reinterpret_cast<const float4*>(ea)[i];
        ushort4 o;
        o.x = __builtin_bit_cast(unsigned short, (__bf16)v.x);
        o.y = __builtin_bit_cast(unsigned short, (__bf16)v.y);
        o.z = __builtin_bit_cast(unsigned short, (__bf16)v.z);
        o.w = __builtin_bit_cast(unsigned short, (__bf16)v.w);
        reinterpret_cast<ushort4*>(ea_b)[i] = o;
    }
}

// ---------------------------------------------------------------------------
// We -> bf16 B-fragments for mfma_f32_16x16x32_bf16.
// WeB[layer][kt*8+ct][lane] holds 8 bf16: B[k = kt*32 + (lane>>4)*8 + j]
//                                         [col = ct*16 + (lane&15)]
// ---------------------------------------------------------------------------
__global__ void prep_we(const float* __restrict__ We, bf16x8* __restrict__ WeB)
{
    const int t = blockIdx.x * blockDim.x + threadIdx.x;
    if (t >= NLAYER * 16 * 64) return;
    const int lane  = t & 63;
    const int frag  = (t >> 6) & 15;
    const int layer = t >> 10;
    const int kt = frag >> 3, ct = frag & 7;
    const int col = ct * 16 + (lane & 15);
    const int k0  = kt * 32 + (lane >> 4) * 8;
    bf16x8 v;
    #pragma unroll
    for (int j = 0; j < 8; ++j)
        v[j] = (__bf16)We[(long long)layer * EDD * HH + (k0 + j) * HH + col];
    WeB[t] = v;
}

// ---------------------------------------------------------------------------
// MFMA aggregation: block per node (grid-stride), 4 waves split 8 col-tiles.
// A-rows gathered from ea_b (original order) via eid_s indirection: each
// random row is one full 128B line consumed by its 4-lane quad.
// C/D layout: col=lane&15, row=(lane>>4)*4+reg. No LDS; We in registers.
// ---------------------------------------------------------------------------
__global__ __launch_bounds__(256) void gine_agg_mfma(
    const float* __restrict__ s,
    const int* __restrict__ src_s,    // dst-sorted src ids, padded to E+16
    const int* __restrict__ eid_s,    // dst-sorted edge ids, padded to E+16
    const int* __restrict__ off,      // [N+1]
    const unsigned short* __restrict__ ea_b,  // [E][64] bf16, original order
    const bf16x8* __restrict__ WeB,   // this layer's 16 frags
    const float* __restrict__ be,
    float* __restrict__ hbuf,         // out: s + agg
    int N)
{
    const int wave = threadIdx.x >> 6;   // col-tiles {2*wave, 2*wave+1}
    const int lane = threadIdx.x & 63;
    const int lmod = lane & 15;
    const int ldiv = lane >> 4;

    const bf16x8 wb00 = WeB[(0 * 8 + 2 * wave    ) * 64 + lane];
    const bf16x8 wb01 = WeB[(0 * 8 + 2 * wave + 1) * 64 + lane];
    const bf16x8 wb10 = WeB[(1 * 8 + 2 * wave    ) * 64 + lane];
    const bf16x8 wb11 = WeB[(1 * 8 + 2 * wave + 1) * 64 + lane];

    const int col0 = (2 * wave)     * 16 + lmod;
    const int col1 = (2 * wave + 1) * 16 + lmod;
    const float bev0 = be[col0];
    const float bev1 = be[col1];

    for (int n = blockIdx.x; n < N; n += gridDim.x) {
        const int p0 = off[n], p1 = off[n + 1];
        float acc0 = 0.f, acc1 = 0.f;

        for (int p = p0; p < p1; p += 16) {
            const int rem = p1 - p;
            // A fragment: row (edge) = eid_s[p+lmod], per-lane 16B at k-offset
            const int rowid = eid_s[p + lmod];
            const unsigned short* arow =
                ea_b + (long long)rowid * EDD + ldiv * 8;
            const bf16x8 a0 = *reinterpret_cast<const bf16x8*>(arow);
            const bf16x8 a1 = *reinterpret_cast<const bf16x8*>(arow + 32);

            const int ms0 = src_s[p + ldiv * 4 + 0];
            const int ms1 = src_s[p + ldiv * 4 + 1];
            const int ms2 = src_s[p + ldiv * 4 + 2];
            const int ms3 = src_s[p + ldiv * 4 + 3];

            f32x4 c0 = {0.f, 0.f, 0.f, 0.f};
            f32x4 c1 = {0.f, 0.f, 0.f, 0.f};
            c0 = __builtin_amdgcn_mfma_f32_16x16x32_bf16(a0, wb00, c0, 0, 0, 0);
            c0 = __builtin_amdgcn_mfma_f32_16x16x32_bf16(a1, wb10, c0, 0, 0, 0);
            c1 = __builtin_amdgcn_mfma_f32_16x16x32_bf16(a0, wb01, c1, 0, 0, 0);
            c1 = __builtin_amdgcn_mfma_f32_16x16x32_bf16(a1, wb11, c1, 0, 0, 0);

            const int base_row = ldiv * 4;
            const int msv[4] = {ms0, ms1, ms2, ms3};
            #pragma unroll
            for (int r = 0; r < 4; ++r) {
                if (base_row + r < rem) {
                    const long long srow = (long long)msv[r] * HH;
                    const float sv0 = s[srow + col0];
                    const float sv1 = s[srow + col1];
                    acc0 += fmaxf(sv0 + c0[r] + bev0, 0.f);
                    acc1 += fmaxf(sv1 + c1[r] + bev1, 0.f);
                }
            }
        }

        // reduce over the 4 row-groups (lanes xor 16, 32)
        acc0 += __shfl_xor(acc0, 16, 64);
        acc0 += __shfl_xor(acc0, 32, 64);
        acc1 += __shfl_xor(acc1, 16, 64);
        acc1 += __shfl_xor(acc1, 32, 64);

        if (ldiv < 2) {
            const int col = (ldiv == 0) ? col0 : col1;
            const float a = (ldiv == 0) ? acc0 : acc1;
            hbuf[(long long)n * HH + col] = s[(long long)n * HH + col] + a;
        }
    }
}

// ---------------------------------------------------------------------------
// Node MLP stage 1 (in place): h -> silu(h @ W1 + b1)
// ---------------------------------------------------------------------------
__global__ __launch_bounds__(256) void gine_node1(
    float* __restrict__ h_t1,
    const float* __restrict__ W1,
    const float* __restrict__ b1,
    int N)
{
    __shared__ float sW[HH * HH];
    for (int i = threadIdx.x; i < HH * HH / 4; i += 256)
        reinterpret_cast<float4*>(sW)[i] = reinterpret_cast<const float4*>(W1)[i];
    __syncthreads();

    const int wave = threadIdx.x >> 6;
    const int lane = threadIdx.x & 63;
    const int c0 = 2 * lane;
    const float bx = b1[c0], by = b1[c0 + 1];

    for (int n = blockIdx.x * 4 + wave; n < N; n += gridDim.x * 4) {
        const float2 hv = *reinterpret_cast<const float2*>(&h_t1[(long long)n * HH + c0]);
        float accx = bx, accy = by;
        #pragma unroll
        for (int m = 0; m < 64; ++m) {
            const float h0 = __uint_as_float(__builtin_amdgcn_readlane(__float_as_uint(hv.x), m));
            const float h1 = __uint_as_float(__builtin_amdgcn_readlane(__float_as_uint(hv.y), m));
            const float2 w0 = *reinterpret_cast<const float2*>(&sW[(2 * m) * HH + c0]);
            const float2 w1 = *reinterpret_cast<const float2*>(&sW[(2 * m + 1) * HH + c0]);
            accx = fmaf(h0, w0.x, accx); accy = fmaf(h0, w0.y, accy);
            accx = fmaf(h1, w1.x, accx); accy = fmaf(h1, w1.y, accy);
        }
        accx = accx / (1.f + __expf(-accx));
        accy = accy / (1.f + __expf(-accy));
        *reinterpret_cast<float2*>(&h_t1[(long long)n * HH + c0]) = make_float2(accx, accy);
    }
}

// ---------------------------------------------------------------------------
// Node MLP stage 2 + residual + LayerNorm + SiLU
// ---------------------------------------------------------------------------
__global__ __launch_bounds__(256) void gine_node2(
    const float* __restrict__ s_in,
    const float* __restrict__ t1,
    const float* __restrict__ W2,
    const float* __restrict__ b2,
    const float* __restrict__ gamma,
    const float* __restrict__ beta,
    float* __restrict__ s_out,
    int N)
{
    __shared__ float sW[HH * HH];
    for (int i = threadIdx.x; i < HH * HH / 4; i += 256)
        reinterpret_cast<float4*>(sW)[i] = reinterpret_cast<const float4*>(W2)[i];
    __syncthreads();

    const int wave = threadIdx.x >> 6;
    const int lane = threadIdx.x & 63;
    const int c0 = 2 * lane;
    const float bx = b2[c0], by = b2[c0 + 1];
    const float gx = gamma[c0], gy = gamma[c0 + 1];
    const float ex = beta[c0], ey = beta[c0 + 1];

    for (int n = blockIdx.x * 4 + wave; n < N; n += gridDim.x * 4) {
        const float2 tv = *reinterpret_cast<const float2*>(&t1[(long long)n * HH + c0]);
        float accx = bx, accy = by;
        #pragma unroll
        for (int m = 0; m < 64; ++m) {
            const float h0 = __uint_as_float(__builtin_amdgcn_readlane(__float_as_uint(tv.x), m));
            const float h1 = __uint_as_float(__builtin_amdgcn_readlane(__float_as_uint(tv.y), m));
            const float2 w0 = *reinterpret_cast<const float2*>(&sW[(2 * m) * HH + c0]);
            const float2 w1 = *reinterpret_cast<const float2*>(&sW[(2 * m + 1) * HH + c0]);
            accx = fmaf(h0, w0.x, accx); accy = fmaf(h0, w0.y, accy);
            accx = fmaf(h1, w1.x, accx); accy = fmaf(h1, w1.y, accy);
        }
        const float2 sv = *reinterpret_cast<const float2*>(&s_in[(long long)n * HH + c0]);
        const float vx = sv.x + accx;
        const float vy = sv.y + accy;

        float sum = vx + vy;
        float ssq = vx * vx + vy * vy;
        #pragma unroll
        for (int o = 32; o > 0; o >>= 1) {
            sum += __shfl_xor(sum, o, 64);
            ssq += __shfl_xor(ssq, o, 64);
        }
        const float mu = sum * (1.0f / HH);
        const float var = ssq * (1.0f / HH) - mu * mu;
        const float rs = rsqrtf(var + LN_EPS);

        float ox = (vx - mu) * rs * gx + ex;
        float oy = (vy - mu) * rs * gy + ey;
        ox = ox / (1.f + __expf(-ox));
        oy = oy / (1.f + __expf(-oy));
        *reinterpret_cast<float2*>(&s_out[(long long)n * HH + c0]) = make_float2(ox, oy);
    }
}

// ---------------------------------------------------------------------------
extern "C" void kernel_launch(void* const* d_in, const int* in_sizes, int n_in,
                              void* d_out, int out_size, void* d_ws, size_t ws_size,
                              hipStream_t stream) {
    const float* s0  = (const float*)d_in[0];
    const int*   ei  = (const int*)  d_in[1];
    const float* ea  = (const float*)d_in[2];
    const float* We  = (const float*)d_in[3];
    const float* be  = (const float*)d_in[4];
    const float* W1  = (const float*)d_in[5];
    const float* b1  = (const float*)d_in[6];
    const float* W2  = (const float*)d_in[7];
    const float* b2  = (const float*)d_in[8];
    const float* gm  = (const float*)d_in[9];
    const float* bt  = (const float*)d_in[10];

    const int NH = in_sizes[0];          // N * 128
    const int N  = NH / HH;
    const int E  = in_sizes[1] / 2;
    const int* src = ei;                 // edge_index[0]
    const int* dst = ei + E;             // edge_index[1]

    // ws layout
    float*          sbuf  = (float*)d_ws;                       // [N*H]
    float*          hbuf  = sbuf + NH;                          // [N*H]
    unsigned short* ea_b  = (unsigned short*)(hbuf + NH);       // [E*64] bf16, orig order
    bf16x8*         WeB   = (bf16x8*)(ea_b + (size_t)E * EDD);  // [3*16*64]
    int*            src_s = (int*)(WeB + NLAYER * 16 * 64);     // [E+16]
    int*            eid_s = src_s + (E + 16);                   // [E+16]
    int*            off   = eid_s + (E + 16);                   // [N+1]
    int*            cursor= off + (N + 1);                      // [N]
    int*            cnt   = cursor + N;                         // [N]

    hipMemcpyAsync(sbuf, s0, sizeof(float) * NH, hipMemcpyDeviceToDevice, stream);

    // ---- one-time preprocessing (edge_index / edge_attr are layer-invariant)
    hipMemsetAsync(cnt, 0, sizeof(int) * N, stream);
    hist_kernel<<<1024, 256, 0, stream>>>(dst, cnt, E);
    scan_kernel<<<1, 1024, 0, stream>>>(cnt, off, N);
    hipMemcpyAsync(cursor, off, sizeof(int) * N, hipMemcpyDeviceToDevice, stream);
    scatter2_kernel<<<1024, 256, 0, stream>>>(src, dst, cursor, src_s, eid_s, E);
    hipMemsetAsync(src_s + E, 0, 16 * sizeof(int), stream);
    hipMemsetAsync(eid_s + E, 0, 16 * sizeof(int), stream);
    conv_ea<<<2048, 256, 0, stream>>>(ea, ea_b, (long long)E * EDD / 4);
    prep_we<<<12, 256, 0, stream>>>(We, WeB);

    for (int l = 0; l < NLAYER; ++l) {
        gine_agg_mfma<<<4096, 256, 0, stream>>>(sbuf, src_s, eid_s, off, ea_b,
                                                WeB + (size_t)l * 16 * 64,
                                                be + l * HH, hbuf, N);
        gine_node1<<<512, 256, 0, stream>>>(hbuf,
                                            W1 + (long long)l * HH * HH,
                                            b1 + l * HH, N);
        float* out = (l == NLAYER - 1) ? (float*)d_out : sbuf;
        gine_node2<<<512, 256, 0, stream>>>(sbuf, hbuf,
                                            W2 + (long long)l * HH * HH,
                                            b2 + l * HH,
                                            gm + l * HH, bt + l * HH,
                                            out, N);
    }
}